// Round 4
// baseline (517.867 us; speedup 1.0000x reference)
//
#include <hip/hip_runtime.h>
#include <hip/hip_cooperative_groups.h>
#include <hip/hip_bf16.h>

namespace cg = cooperative_groups;

#define ROWS 1025   // B*N + 1
#define DD   128    // D
#define C3   384    // 3*D
#define BB   8
#define NN   128
#define GTAB_UNITS 771    // 257 row-chunks x 3 col-chunks
#define COOP_GRID  512    // 2 blocks/CU needed; capacity 4/CU -> safe margin

__device__ __forceinline__ float fsigmoid(float x) {
    return __builtin_amdgcn_rcpf(1.0f + __expf(-x));
}
__device__ __forceinline__ float ftanh(float x) {
    return 1.0f - 2.0f * __builtin_amdgcn_rcpf(__expf(2.0f * x) + 1.0f);
}
__device__ __forceinline__ float bf2f(unsigned short u) {
    return __uint_as_float(((unsigned int)u) << 16);
}
__device__ __forceinline__ unsigned short f2bf(float f) {
    unsigned int i = __float_as_uint(f);            // finite data only
    return (unsigned short)((i + 0x7FFFu + ((i >> 16) & 1u)) >> 16);
}

struct SMem {
    union {
        float hs[4][DD];                 // gtab stage: 2 KB
        struct {
            int   ps[NN];                // phase stage: parent idx col
            int   cs[NN];                // child idx col
            float sacc[2][DD];           // partial sums
        } ph;
    };
};

// Gate tables, packed bf16x4 per (row, d):
//   GiP[row][d] = {ir, iz, in, 0},  GhP[row][d] = {hr, hz, hn, h}
// Unit = (row-chunk of 4 rows) x (col-chunk of 256 combined cols out of 768).
__device__ void gtab_stage(int unit, int t,
    const float* __restrict__ h,
    const float* __restrict__ Wi, const float* __restrict__ Wh,
    const float* __restrict__ bi, const float* __restrict__ bh,
    unsigned short* __restrict__ GiP, unsigned short* __restrict__ GhP,
    SMem& sm) {
    const int rblk = unit / 3, cch = unit % 3;
    const int r0 = rblk * 4;
    for (int idx = t; idx < 4 * DD; idx += 256) {
        int r = idx >> 7, k = idx & (DD - 1);
        sm.hs[r][k] = (r0 + r < ROWS) ? h[(size_t)(r0 + r) * DD + k] : 0.0f;
    }
    __syncthreads();
    if (cch == 0 && t < DD) {
#pragma unroll
        for (int r = 0; r < 4; ++r)
            if (r0 + r < ROWS) GhP[(size_t)(r0 + r) * 512 + t * 4 + 3] = f2bf(sm.hs[r][t]);
    }
    const int  c   = cch * 256 + t;      // combined col 0..767
    const bool isI = (c < C3);
    const int  cc  = isI ? c : c - C3;
    const float* __restrict__ w = (isI ? Wi : Wh) + (size_t)cc * DD;
    float acc[4] = {0.f, 0.f, 0.f, 0.f};
    for (int k = 0; k < DD; k += 4) {
        float4 wv = *reinterpret_cast<const float4*>(w + k);
#pragma unroll
        for (int r = 0; r < 4; ++r) {
            acc[r] += sm.hs[r][k] * wv.x + sm.hs[r][k + 1] * wv.y
                    + sm.hs[r][k + 2] * wv.z + sm.hs[r][k + 3] * wv.w;
        }
    }
    const float bv = (isI ? bi : bh)[cc];
    unsigned short* __restrict__ G = isI ? GiP : GhP;
    const int s = cc >> 7, d = cc & (DD - 1);
#pragma unroll
    for (int r = 0; r < 4; ++r)
        if (r0 + r < ROWS) G[(size_t)(r0 + r) * 512 + d * 4 + s] = f2bf(acc[r] + bv);
    __syncthreads();                     // LDS reused by next unit / next stage
}

// One unit per (b,j) output column; 256 threads = (ic 0..1) x (d 0..127).
// XC=1: x=child,h=parent (bwd). XC=0: x=parent,h=child (fwd).
template<int XC, int WRITE_OUT>
__device__ void phase_stage(int col, int t,
    const float* __restrict__ hin,
    const int* __restrict__ parent, const int* __restrict__ child,
    const unsigned short* __restrict__ GiP, const unsigned short* __restrict__ GhP,
    float* __restrict__ hout,
    const int* __restrict__ tgt, float* __restrict__ out,
    SMem& sm) {
    const int b = col >> 7, j = col & (NN - 1);
    const size_t base = (size_t)b * NN * NN + j;         // + i*NN
    if (t < NN)  sm.ph.ps[t]      = parent[base + (size_t)t * NN];
    else         sm.ph.cs[t - NN] = child [base + (size_t)(t - NN) * NN];
    __syncthreads();

    const int ic = t >> 7, d = t & (DD - 1);
    float acc = 0.0f;
#pragma unroll 4
    for (int k = 0; k < 64; ++k) {
        const int i  = ic * 64 + k;
        const int p  = sm.ph.ps[i];
        const int c  = sm.ph.cs[i];
        const int xi = XC ? c : p;
        const int hi = XC ? p : c;
        const ushort4 vx = *reinterpret_cast<const ushort4*>(GiP + (size_t)xi * 512 + d * 4);
        const ushort4 vh = *reinterpret_cast<const ushort4*>(GhP + (size_t)hi * 512 + d * 4);
        const float ir = bf2f(vx.x), iz = bf2f(vx.y), in_ = bf2f(vx.z);
        const float hr = bf2f(vh.x), hz = bf2f(vh.y), hn = bf2f(vh.z), hv = bf2f(vh.w);
        const float r = fsigmoid(ir + hr);
        const float z = fsigmoid(iz + hz);
        const float n = ftanh(in_ + r * hn);
        acc += (1.0f - z) * n + z * hv;
    }
    sm.ph.sacc[ic][d] = acc;
    __syncthreads();

    if (ic == 0) {
        const float v   = sm.ph.sacc[0][d] + sm.ph.sacc[1][d];
        const int   row = 1 + col;
        const float res = hin[(size_t)row * DD + d] + v;
        if (WRITE_OUT) {
#pragma unroll
            for (int bb = 0; bb < BB; ++bb)
                if (tgt[bb] == row) out[bb * DD + d] = res;
        } else {
            hout[(size_t)row * DD + d] = res;
        }
    } else if (ic == 1 && col == 0 && !WRITE_OUT) {
        hout[d] = hin[d];                 // row 0 unchanged (tgt >= 1 always)
    }
    __syncthreads();                      // LDS reused by next unit
}

// ---------- fused cooperative kernel ----------
__global__ __launch_bounds__(256, 4) void fused_kernel(
    const float* __restrict__ hidden,
    const int* __restrict__ parent, const int* __restrict__ child,
    const int* __restrict__ tgt,
    const float* __restrict__ Wif, const float* __restrict__ Whf,
    const float* __restrict__ bif, const float* __restrict__ bhf,
    const float* __restrict__ Wib, const float* __restrict__ Whb,
    const float* __restrict__ bib, const float* __restrict__ bhb,
    unsigned short* __restrict__ GiP, unsigned short* __restrict__ GhP,
    float* __restrict__ h1, float* __restrict__ out) {
    cg::grid_group grid = cg::this_grid();
    __shared__ SMem sm;
    const int bid = blockIdx.x, t = threadIdx.x;

    for (int u = bid; u < GTAB_UNITS; u += COOP_GRID)
        gtab_stage(u, t, hidden, Wib, Whb, bib, bhb, GiP, GhP, sm);
    grid.sync();
    for (int u = bid; u < BB * NN; u += COOP_GRID)
        phase_stage<1, 0>(u, t, hidden, parent, child, GiP, GhP, h1, nullptr, nullptr, sm);
    grid.sync();
    for (int u = bid; u < GTAB_UNITS; u += COOP_GRID)
        gtab_stage(u, t, h1, Wif, Whf, bif, bhf, GiP, GhP, sm);
    grid.sync();
    for (int u = bid; u < BB * NN; u += COOP_GRID)
        phase_stage<0, 1>(u, t, h1, parent, child, GiP, GhP, nullptr, tgt, out, sm);
}

// ---------- fallback (separate kernels) ----------
__global__ __launch_bounds__(256) void gtab_kernel(
    const float* __restrict__ h,
    const float* __restrict__ Wi, const float* __restrict__ Wh,
    const float* __restrict__ bi, const float* __restrict__ bh,
    unsigned short* __restrict__ GiP, unsigned short* __restrict__ GhP) {
    __shared__ SMem sm;
    gtab_stage(blockIdx.x, threadIdx.x, h, Wi, Wh, bi, bh, GiP, GhP, sm);
}

template<int XC, int WRITE_OUT>
__global__ __launch_bounds__(256) void phase_kernel(
    const float* __restrict__ hin,
    const int* __restrict__ parent, const int* __restrict__ child,
    const unsigned short* __restrict__ GiP, const unsigned short* __restrict__ GhP,
    float* __restrict__ hout,
    const int* __restrict__ tgt, float* __restrict__ out) {
    __shared__ SMem sm;
    phase_stage<XC, WRITE_OUT>(blockIdx.x, threadIdx.x, hin, parent, child,
                               GiP, GhP, hout, tgt, out, sm);
}

extern "C" void kernel_launch(void* const* d_in, const int* in_sizes, int n_in,
                              void* d_out, int out_size, void* d_ws, size_t ws_size,
                              hipStream_t stream) {
    const float* hidden = (const float*)d_in[0];
    const int*   parent = (const int*)d_in[1];
    const int*   child  = (const int*)d_in[2];
    const int*   tgt    = (const int*)d_in[3];
    const float* Wif    = (const float*)d_in[4];
    const float* Whf    = (const float*)d_in[5];
    const float* bif    = (const float*)d_in[6];
    const float* bhf    = (const float*)d_in[7];
    const float* Wib    = (const float*)d_in[8];
    const float* Whb    = (const float*)d_in[9];
    const float* bib    = (const float*)d_in[10];
    const float* bhb    = (const float*)d_in[11];

    char* ws = (char*)d_ws;
    unsigned short* GiP = (unsigned short*)(ws);                  // 1025*512 bf16
    unsigned short* GhP = (unsigned short*)(ws + 1049600);        // 1025*512 bf16
    float*          h1  = (float*)(ws + 2099200);                 // 1025*128 f32
    float*          out = (float*)d_out;

    void* args[] = {
        (void*)&hidden, (void*)&parent, (void*)&child, (void*)&tgt,
        (void*)&Wif, (void*)&Whf, (void*)&bif, (void*)&bhf,
        (void*)&Wib, (void*)&Whb, (void*)&bib, (void*)&bhb,
        (void*)&GiP, (void*)&GhP, (void*)&h1, (void*)&out,
    };
    hipError_t e = hipLaunchCooperativeKernel((const void*)fused_kernel,
                                              dim3(COOP_GRID), dim3(256),
                                              args, 0, stream);
    if (e != hipSuccess) {
        (void)hipGetLastError();   // clear sticky error, use fallback path
        gtab_kernel<<<GTAB_UNITS, 256, 0, stream>>>(hidden, Wib, Whb, bib, bhb, GiP, GhP);
        phase_kernel<1, 0><<<BB * NN, 256, 0, stream>>>(hidden, parent, child, GiP, GhP, h1, nullptr, nullptr);
        gtab_kernel<<<GTAB_UNITS, 256, 0, stream>>>(h1, Wif, Whf, bif, bhf, GiP, GhP);
        phase_kernel<0, 1><<<BB * NN, 256, 0, stream>>>(h1, parent, child, GiP, GhP, nullptr, tgt, out);
    }
}